// Round 8
// baseline (419.133 us; speedup 1.0000x reference)
//
#include <hip/hip_runtime.h>
#include <hip/hip_bf16.h>

#define NE 800000
#define NV 100000
#define NNZN 1600000
#define D 128
#define SLOT_CAP 64   // slots per vertex; P(Poisson(16) > 63) ~ 1e-18, clamped
#define SC_BLOCKS 8192

typedef short short8 __attribute__((ext_vector_type(8)));
typedef short s16x4 __attribute__((ext_vector_type(4)));
typedef float f32x4 __attribute__((ext_vector_type(4)));
typedef float f32x8 __attribute__((ext_vector_type(8)));
typedef _Float16 h8v __attribute__((ext_vector_type(8)));

__device__ __forceinline__ unsigned short f2bfu(float f) {
  union { float f; unsigned u; } x;
  x.f = f;
  unsigned u = x.u;
  u += ((u >> 16) & 1u) + 0x7FFFu;  // round-to-nearest-even
  return (unsigned short)(u >> 16);
}

__device__ __forceinline__ float fsigmoid(float x) {
  return 1.0f / (1.0f + __expf(-x));
}
__device__ __forceinline__ float ftanh(float x) {
  return 2.0f / (1.0f + __expf(-2.0f * x)) - 1.0f;
}

__device__ __forceinline__ f32x8 h2f8(h8v h) {
  f32x8 r;
#pragma unroll
  for (int k = 0; k < 8; ++k) r[k] = (float)h[k];
  return r;
}

// ---------------- Phase 0: W/bias prep + counts zeroing ----------------
// Wcat layout: 16B chunks indexed c8 = (((wid*8+kk)*4+g)*2+t)*64 + (l16*4+lhi)
// so each MFMA B-fragment wave-load in the lstm kernel is one contiguous
// 1 KB segment.
__global__ __launch_bounds__(256) void wconv_kernel(
    const float* __restrict__ W_ih, const float* __restrict__ W_hh,
    const float* __restrict__ b_ih, const float* __restrict__ b_hh,
    short* __restrict__ Wcat, float* __restrict__ bcomb,
    int* __restrict__ counts) {
  int idx = blockIdx.x * 256 + threadIdx.x;  // 512*256 = 131072 total
  if (idx < 16384) {
    int c8 = idx;
    int pos = c8 & 63;
    int t   = (c8 >> 6) & 1;
    int g   = (c8 >> 7) & 3;
    int kk  = (c8 >> 9) & 7;
    int wid = (c8 >> 12) & 3;
    int n = g * 128 + wid * 32 + t * 16 + (pos >> 2);
    int k0 = kk * 32 + (pos & 3) * 8;
    const float* src = (k0 < 128) ? (W_ih + (size_t)n * 128 + k0)
                                  : (W_hh + (size_t)n * 128 + (k0 - 128));
    f32x4 a = *(const f32x4*)(src);
    f32x4 b = *(const f32x4*)(src + 4);
    short8 v;
    v[0] = (short)f2bfu(a[0]); v[1] = (short)f2bfu(a[1]);
    v[2] = (short)f2bfu(a[2]); v[3] = (short)f2bfu(a[3]);
    v[4] = (short)f2bfu(b[0]); v[5] = (short)f2bfu(b[1]);
    v[6] = (short)f2bfu(b[2]); v[7] = (short)f2bfu(b[3]);
    *(short8*)(Wcat + (size_t)c8 * 8) = v;
  }
  if (idx < 512) bcomb[idx] = b_ih[idx] + b_hh[idx];
  if (idx < NV) counts[idx] = 0;
}

// ---------------- Phase 1 (main path): scatter + fp16 conversion -----------
// Scatter is latency/atomic-bound; the x_e->fp16 streaming conversion is
// BW-bound. Fused in one kernel they overlap across blocks. x_h (205 MB)
// halves the gather's 128B-line count per edge (256B rows vs 512B) -- the
// lever for a request-concurrency-capped gather (R5/R6/R7 showed throughput
// flat vs occupancy, L3 residency, and per-wave ILP). NT loads on x_e (read
// once); regular stores so x_h lands in L3 (fits: 205 < 256 MB).
__global__ __launch_bounds__(256) void scatcon_kernel(
    const int* __restrict__ eid, const int* __restrict__ vid,
    int* __restrict__ counts, int* __restrict__ slots,
    const float* __restrict__ x_e, _Float16* __restrict__ x_h) {
  unsigned j = blockIdx.x * 256 + threadIdx.x;
  if (j < NNZN) {
    int v = vid[j];
    int pos = atomicAdd(&counts[v], 1);
    if (pos < SLOT_CAP) slots[(size_t)v * SLOT_CAP + pos] = eid[j];
  }
  const unsigned NU = (unsigned)NE * 16u;  // 12.8M units of 8 floats
  for (unsigned u = j; u < NU; u += SC_BLOCKS * 256u) {
    f32x4 a = __builtin_nontemporal_load((const f32x4*)(x_e + (size_t)u * 8));
    f32x4 b = __builtin_nontemporal_load((const f32x4*)(x_e + (size_t)u * 8 + 4));
    h8v h;
    h[0] = (_Float16)a[0]; h[1] = (_Float16)a[1];
    h[2] = (_Float16)a[2]; h[3] = (_Float16)a[3];
    h[4] = (_Float16)b[0]; h[5] = (_Float16)b[1];
    h[6] = (_Float16)b[2]; h[7] = (_Float16)b[3];
    *(h8v*)(x_h + (size_t)u * 8) = h;
  }
}

// ---------------- Phase 1 (fallback, small ws): plain scatter ---------------
__global__ __launch_bounds__(256) void scatter_direct_kernel(
    const int* __restrict__ eid, const int* __restrict__ vid,
    int* __restrict__ counts, int* __restrict__ slots) {
  int j = blockIdx.x * 256 + threadIdx.x;
  if (j < NNZN) {
    int v = vid[j];
    int pos = atomicAdd(&counts[v], 1);
    if (pos < SLOT_CAP) slots[(size_t)v * SLOT_CAP + pos] = eid[j];
  }
}

// ---------------- Phase 2 (main path): fp16 gather, 4 rows/instruction ------
// One wave per vertex. 64 lanes = 4 edge-slot groups (grp = lane>>4) x 16
// 16B-chunks (p16 = lane&15): one dwordx4 wave-load covers FOUR 256B fp16
// rows -> per 32-edge volley only 8 instructions / 2 lines per edge (halved
// vs f32). Typical deg-16 vertex = ONE masked volley. Accumulate f32,
// reduce across groups with xor-32/xor-16 shuffles, write bf16 msg.
__global__ __launch_bounds__(256, 4) void gather16_kernel(
    const _Float16* __restrict__ x_h, const int* __restrict__ counts,
    const int* __restrict__ slots, char* __restrict__ msgb) {
  __shared__ int slds[4][SLOT_CAP];
  const int tid = threadIdx.x;
  const int wid = tid >> 6;
  const int lane = tid & 63;
  const int v = blockIdx.x * 4 + wid;  // NV % 4 == 0
  const int grp = lane >> 4;   // edge-slot group 0..3
  const int p16 = lane & 15;   // features [p16*8, p16*8+8)
  int deg = counts[v];
  deg = deg > SLOT_CAP ? SLOT_CAP : deg;
  slds[wid][lane] = slots[(size_t)v * SLOT_CAP + lane];
  const int* row_ids = slds[wid];

  f32x8 A0 = {0.f,0.f,0.f,0.f,0.f,0.f,0.f,0.f};
  f32x8 A1 = A0, A2 = A0, A3 = A0;
  const f32x8 Z = A0;
  const int nfull = deg >> 5;   // full 32-edge volleys
  const int rem = deg & 31;
#pragma unroll 1
  for (int c = 0; c < nfull; ++c) {
    int b = c * 32 + grp;
    int e0 = row_ids[b];      int e1 = row_ids[b + 4];
    int e2 = row_ids[b + 8];  int e3 = row_ids[b + 12];
    int e4 = row_ids[b + 16]; int e5 = row_ids[b + 20];
    int e6 = row_ids[b + 24]; int e7 = row_ids[b + 28];
    h8v t0 = *(const h8v*)(x_h + (size_t)e0 * D + p16 * 8);
    h8v t1 = *(const h8v*)(x_h + (size_t)e1 * D + p16 * 8);
    h8v t2 = *(const h8v*)(x_h + (size_t)e2 * D + p16 * 8);
    h8v t3 = *(const h8v*)(x_h + (size_t)e3 * D + p16 * 8);
    h8v t4 = *(const h8v*)(x_h + (size_t)e4 * D + p16 * 8);
    h8v t5 = *(const h8v*)(x_h + (size_t)e5 * D + p16 * 8);
    h8v t6 = *(const h8v*)(x_h + (size_t)e6 * D + p16 * 8);
    h8v t7 = *(const h8v*)(x_h + (size_t)e7 * D + p16 * 8);
    A0 += h2f8(t0); A1 += h2f8(t1); A2 += h2f8(t2); A3 += h2f8(t3);
    A0 += h2f8(t4); A1 += h2f8(t5); A2 += h2f8(t6); A3 += h2f8(t7);
  }
  if (rem) {  // one masked 32-edge volley: 8 loads in flight, no serial tail
    int b = nfull * 32 + grp;
    int i0 = b,      i1 = b + 4,  i2 = b + 8,  i3 = b + 12;
    int i4 = b + 16, i5 = b + 20, i6 = b + 24, i7 = b + 28;
    int e0 = row_ids[i0 < deg ? i0 : 0];
    int e1 = row_ids[i1 < deg ? i1 : 0];
    int e2 = row_ids[i2 < deg ? i2 : 0];
    int e3 = row_ids[i3 < deg ? i3 : 0];
    int e4 = row_ids[i4 < deg ? i4 : 0];
    int e5 = row_ids[i5 < deg ? i5 : 0];
    int e6 = row_ids[i6 < deg ? i6 : 0];
    int e7 = row_ids[i7 < deg ? i7 : 0];
    h8v t0 = *(const h8v*)(x_h + (size_t)e0 * D + p16 * 8);
    h8v t1 = *(const h8v*)(x_h + (size_t)e1 * D + p16 * 8);
    h8v t2 = *(const h8v*)(x_h + (size_t)e2 * D + p16 * 8);
    h8v t3 = *(const h8v*)(x_h + (size_t)e3 * D + p16 * 8);
    h8v t4 = *(const h8v*)(x_h + (size_t)e4 * D + p16 * 8);
    h8v t5 = *(const h8v*)(x_h + (size_t)e5 * D + p16 * 8);
    h8v t6 = *(const h8v*)(x_h + (size_t)e6 * D + p16 * 8);
    h8v t7 = *(const h8v*)(x_h + (size_t)e7 * D + p16 * 8);
    A0 += (i0 < deg) ? h2f8(t0) : Z;
    A1 += (i1 < deg) ? h2f8(t1) : Z;
    A2 += (i2 < deg) ? h2f8(t2) : Z;
    A3 += (i3 < deg) ? h2f8(t3) : Z;
    A0 += (i4 < deg) ? h2f8(t4) : Z;
    A1 += (i5 < deg) ? h2f8(t5) : Z;
    A2 += (i6 < deg) ? h2f8(t6) : Z;
    A3 += (i7 < deg) ? h2f8(t7) : Z;
  }
  A0 += A1;
  A2 += A3;
  A0 += A2;
  // reduce across the 4 edge-slot groups (lane^32, lane^16)
#pragma unroll
  for (int f = 0; f < 8; ++f) {
    float x = A0[f];
    x += __shfl_xor(x, 32);
    x += __shfl_xor(x, 16);
    A0[f] = x;
  }
  if (lane < 16) {
    short8 p;
#pragma unroll
    for (int f = 0; f < 8; ++f) p[f] = (short)f2bfu(A0[f]);
    *(short8*)(msgb + (size_t)v * 512 + p16 * 16) = p;
  }
}

// ---------------- Phase 2 (fallback): f32 gather (R7 structure) -------------
__global__ __launch_bounds__(256, 4) void gather_kernel(
    const float* __restrict__ x_e, const int* __restrict__ counts,
    const int* __restrict__ slots, char* __restrict__ msgb) {
  __shared__ int slds[4][SLOT_CAP];
  const int tid = threadIdx.x;
  const int wid = tid >> 6;
  const int lane = tid & 63;
  const int v = blockIdx.x * 4 + wid;
  const int half = lane >> 5;
  const int pos = lane & 31;
  int deg = counts[v];
  deg = deg > SLOT_CAP ? SLOT_CAP : deg;
  slds[wid][lane] = slots[(size_t)v * SLOT_CAP + lane];
  const int* row_ids = slds[wid];

  f32x4 a0 = {0.f, 0.f, 0.f, 0.f}, a1 = a0, a2 = a0, a3 = a0;
  const int nfull = deg >> 4;
  const int rem = deg & 15;
#pragma unroll 1
  for (int c = 0; c < nfull; ++c) {
    int b = c * 16 + half;
    int e0 = row_ids[b];      int e1 = row_ids[b + 2];
    int e2 = row_ids[b + 4];  int e3 = row_ids[b + 6];
    int e4 = row_ids[b + 8];  int e5 = row_ids[b + 10];
    int e6 = row_ids[b + 12]; int e7 = row_ids[b + 14];
    a0 += *(const f32x4*)(x_e + (size_t)e0 * D + pos * 4);
    a1 += *(const f32x4*)(x_e + (size_t)e1 * D + pos * 4);
    a2 += *(const f32x4*)(x_e + (size_t)e2 * D + pos * 4);
    a3 += *(const f32x4*)(x_e + (size_t)e3 * D + pos * 4);
    a0 += *(const f32x4*)(x_e + (size_t)e4 * D + pos * 4);
    a1 += *(const f32x4*)(x_e + (size_t)e5 * D + pos * 4);
    a2 += *(const f32x4*)(x_e + (size_t)e6 * D + pos * 4);
    a3 += *(const f32x4*)(x_e + (size_t)e7 * D + pos * 4);
  }
  if (rem) {
    int b = nfull * 16 + half;
    f32x4 z = {0.f, 0.f, 0.f, 0.f};
    int i0 = b,      i1 = b + 2,  i2 = b + 4,  i3 = b + 6;
    int i4 = b + 8,  i5 = b + 10, i6 = b + 12, i7 = b + 14;
    int e0 = row_ids[i0 < deg ? i0 : 0];
    int e1 = row_ids[i1 < deg ? i1 : 0];
    int e2 = row_ids[i2 < deg ? i2 : 0];
    int e3 = row_ids[i3 < deg ? i3 : 0];
    int e4 = row_ids[i4 < deg ? i4 : 0];
    int e5 = row_ids[i5 < deg ? i5 : 0];
    int e6 = row_ids[i6 < deg ? i6 : 0];
    int e7 = row_ids[i7 < deg ? i7 : 0];
    f32x4 t0 = *(const f32x4*)(x_e + (size_t)e0 * D + pos * 4);
    f32x4 t1 = *(const f32x4*)(x_e + (size_t)e1 * D + pos * 4);
    f32x4 t2 = *(const f32x4*)(x_e + (size_t)e2 * D + pos * 4);
    f32x4 t3 = *(const f32x4*)(x_e + (size_t)e3 * D + pos * 4);
    f32x4 t4 = *(const f32x4*)(x_e + (size_t)e4 * D + pos * 4);
    f32x4 t5 = *(const f32x4*)(x_e + (size_t)e5 * D + pos * 4);
    f32x4 t6 = *(const f32x4*)(x_e + (size_t)e6 * D + pos * 4);
    f32x4 t7 = *(const f32x4*)(x_e + (size_t)e7 * D + pos * 4);
    a0 += (i0 < deg) ? t0 : z;
    a1 += (i1 < deg) ? t1 : z;
    a2 += (i2 < deg) ? t2 : z;
    a3 += (i3 < deg) ? t3 : z;
    a0 += (i4 < deg) ? t4 : z;
    a1 += (i5 < deg) ? t5 : z;
    a2 += (i6 < deg) ? t6 : z;
    a3 += (i7 < deg) ? t7 : z;
  }
  a0 += a1;
  a2 += a3;
  a0 += a2;
  f32x4 b;
  b[0] = __shfl_xor(a0[0], 32);
  b[1] = __shfl_xor(a0[1], 32);
  b[2] = __shfl_xor(a0[2], 32);
  b[3] = __shfl_xor(a0[3], 32);
  a0 += b;
  if (half == 0) {
    s16x4 p;
    p[0] = (short)f2bfu(a0[0]);
    p[1] = (short)f2bfu(a0[1]);
    p[2] = (short)f2bfu(a0[2]);
    p[3] = (short)f2bfu(a0[3]);
    *(s16x4*)(msgb + (size_t)v * 512 + pos * 8) = p;
  }
}

// ---------------- Phase 3: GEMM + LSTM cell ----------------
// Block = 256 threads (4 waves), 32 vertices.
// A tile: [32 rows][256 k] bf16 in LDS (XOR-swizzled, row stride 512B),
// cols 0..15 = msg (bf16, read from out_c rows this block will overwrite),
// cols 16..31 = h_v (bf16). Wave wid owns feature slice [wid*32, wid*32+32).
__global__ __launch_bounds__(256) void lstm_kernel(
    const char* __restrict__ msgb, const float* __restrict__ h_v,
    const float* __restrict__ c_v, const short* __restrict__ Wcat,
    const float* __restrict__ bcomb, float* __restrict__ out) {
  __shared__ char Atile[32 * 256 * 2];  // 16 KB
  const int tid = threadIdx.x;
  const int vbase = blockIdx.x * 32;

#pragma unroll
  for (int i = 0; i < 4; ++i) {
    int cid = tid + i * 256;  // 0..1023 = 32 rows x 32 16B-chunks
    int row = cid >> 5;
    int c = cid & 31;
    short8 v;
    if (c < 16) {
      v = *(const short8*)(msgb + (size_t)(vbase + row) * 512 + c * 16);
    } else {
      const float* src = h_v + (size_t)(vbase + row) * D + (c - 16) * 8;
      f32x4 a = *(const f32x4*)(src);
      f32x4 b = *(const f32x4*)(src + 4);
      v[0] = (short)f2bfu(a[0]); v[1] = (short)f2bfu(a[1]);
      v[2] = (short)f2bfu(a[2]); v[3] = (short)f2bfu(a[3]);
      v[4] = (short)f2bfu(b[0]); v[5] = (short)f2bfu(b[1]);
      v[6] = (short)f2bfu(b[2]); v[7] = (short)f2bfu(b[3]);
    }
    int byteoff = (row * 512 + c * 16) ^ ((row & 7) << 4);
    *(short8*)(Atile + byteoff) = v;
  }
  __syncthreads();

  const int wid = tid >> 6;
  const int lane = tid & 63;
  const int l16 = lane & 15;
  const int lhi = lane >> 4;  // 0..3

  f32x4 acc[2][4][2] = {};  // [m-tile][gate][d-subtile]

#pragma unroll
  for (int kk = 0; kk < 8; ++kk) {
    short8 afrag[2];
#pragma unroll
    for (int m = 0; m < 2; ++m) {
      int row = m * 16 + l16;
      int byteoff = (row * 512 + kk * 64 + lhi * 16) ^ ((row & 7) << 4);
      afrag[m] = *(const short8*)(Atile + byteoff);
    }
#pragma unroll
    for (int g = 0; g < 4; ++g) {
#pragma unroll
      for (int t = 0; t < 2; ++t) {
        // coalesced Wcat layout: contiguous 1KB per wave-load
        size_t boff = (size_t)(wid * 64 + kk * 8 + g * 2 + t) * 1024
                    + (size_t)(l16 * 4 + lhi) * 16;
        short8 bfrag = *(const short8*)((const char*)Wcat + boff);
        acc[0][g][t] = __builtin_amdgcn_mfma_f32_16x16x32_bf16(afrag[0], bfrag, acc[0][g][t], 0, 0, 0);
        acc[1][g][t] = __builtin_amdgcn_mfma_f32_16x16x32_bf16(afrag[1], bfrag, acc[1][g][t], 0, 0, 0);
      }
    }
  }

  float* out_h = out;
  float* out_c = out + (size_t)NV * D;
#pragma unroll
  for (int m = 0; m < 2; ++m) {
#pragma unroll
    for (int t = 0; t < 2; ++t) {
      int d = wid * 32 + t * 16 + l16;
      float bi = bcomb[d];
      float bf = bcomb[128 + d];
      float bg = bcomb[256 + d];
      float bo = bcomb[384 + d];
#pragma unroll
      for (int r = 0; r < 4; ++r) {
        int v = vbase + m * 16 + lhi * 4 + r;
        float gi = acc[m][0][t][r] + bi;
        float gf = acc[m][1][t][r] + bf;
        float gg = acc[m][2][t][r] + bg;
        float go = acc[m][3][t][r] + bo;
        float ii = fsigmoid(gi);
        float ff = fsigmoid(gf);
        float g_ = ftanh(gg);
        float oo = fsigmoid(go);
        float cv = c_v[(size_t)v * D + d];
        float cn = ff * cv + ii * g_;
        float hn = oo * ftanh(cn);
        out_h[(size_t)v * D + d] = hn;
        out_c[(size_t)v * D + d] = cn;
      }
    }
  }
}

extern "C" void kernel_launch(void* const* d_in, const int* in_sizes, int n_in,
                              void* d_out, int out_size, void* d_ws, size_t ws_size,
                              hipStream_t stream) {
  const float* x_e  = (const float*)d_in[0];
  const float* h_v  = (const float*)d_in[1];
  const float* c_v  = (const float*)d_in[2];
  const float* W_ih = (const float*)d_in[3];
  const float* W_hh = (const float*)d_in[4];
  const float* b_ih = (const float*)d_in[5];
  const float* b_hh = (const float*)d_in[6];
  const int* eid    = (const int*)d_in[7];
  const int* vid    = (const int*)d_in[8];
  // d_in[9] = v_batch: unused by the reference computation.
  float* out = (float*)d_out;

  // ws layout: Wcat bf16[512*256] | bcomb f32[512] | counts[NV] |
  //            slots int[NV*SLOT_CAP] | x_h fp16[NE*D] (main path only)
  char* w = (char*)d_ws;
  short* Wcat  = (short*)w;                 w += 512 * 256 * sizeof(short);
  float* bcomb = (float*)w;                 w += 512 * sizeof(float);
  int* counts  = (int*)w;                   w += NV * sizeof(int);
  int* slots   = (int*)w;                   w += (size_t)NV * SLOT_CAP * sizeof(int);
  _Float16* x_h = (_Float16*)w;

  const size_t need = 512 * 256 * sizeof(short) + 512 * sizeof(float)
                    + (size_t)NV * sizeof(int)
                    + (size_t)NV * SLOT_CAP * sizeof(int)
                    + (size_t)NE * D * sizeof(_Float16);

  // bf16 msg lives in the low 256B of each 512B out_c row (no extra ws;
  // lstm block b reads only the rows it later overwrites).
  char* msgb = (char*)(out + (size_t)NV * D);

  wconv_kernel<<<512, 256, 0, stream>>>(W_ih, W_hh, b_ih, b_hh, Wcat, bcomb, counts);
  if (ws_size >= need) {
    scatcon_kernel<<<SC_BLOCKS, 256, 0, stream>>>(eid, vid, counts, slots, x_e, x_h);
    gather16_kernel<<<NV / 4, 256, 0, stream>>>(x_h, counts, slots, msgb);
  } else {
    scatter_direct_kernel<<<(NNZN + 255) / 256, 256, 0, stream>>>(eid, vid, counts, slots);
    gather_kernel<<<NV / 4, 256, 0, stream>>>(x_e, counts, slots, msgb);
  }
  lstm_kernel<<<NV / 32, 256, 0, stream>>>(msgb, h_v, c_v, Wcat, bcomb, out);
}

// Round 9
// 405.411 us; speedup vs baseline: 1.0338x; 1.0338x over previous
//
#include <hip/hip_runtime.h>
#include <hip/hip_bf16.h>

#define NE 800000
#define NV 100000
#define NNZN 1600000
#define D 128
#define SLOT_CAP 64   // slots per vertex; P(Poisson(16) > 63) ~ 1e-18, clamped
#define XCUT 400000   // edges < XCUT have fp16 rows in the out buffer
#define SC_BLOCKS 8192

typedef short short8 __attribute__((ext_vector_type(8)));
typedef short s16x4 __attribute__((ext_vector_type(4)));
typedef float f32x4 __attribute__((ext_vector_type(4)));
typedef float f32x8 __attribute__((ext_vector_type(8)));
typedef _Float16 h8v __attribute__((ext_vector_type(8)));

__device__ __forceinline__ unsigned short f2bfu(float f) {
  union { float f; unsigned u; } x;
  x.f = f;
  unsigned u = x.u;
  u += ((u >> 16) & 1u) + 0x7FFFu;  // round-to-nearest-even
  return (unsigned short)(u >> 16);
}

__device__ __forceinline__ float fsigmoid(float x) {
  return 1.0f / (1.0f + __expf(-x));
}
__device__ __forceinline__ float ftanh(float x) {
  return 2.0f / (1.0f + __expf(-2.0f * x)) - 1.0f;
}

__device__ __forceinline__ f32x8 h2f8(h8v h) {
  f32x8 r;
#pragma unroll
  for (int k = 0; k < 8; ++k) r[k] = (float)h[k];
  return r;
}

// ---------------- Phase 0: W/bias prep + counters zeroing ----------------
// Wcat layout: 16B chunks indexed c8 = (((wid*8+kk)*4+g)*2+t)*64 + (l16*4+lhi)
// so each MFMA B-fragment wave-load in the lstm kernel is one contiguous
// 1 KB segment.
__global__ __launch_bounds__(256) void wconv_kernel(
    const float* __restrict__ W_ih, const float* __restrict__ W_hh,
    const float* __restrict__ b_ih, const float* __restrict__ b_hh,
    short* __restrict__ Wcat, float* __restrict__ bcomb,
    int* __restrict__ counts, int* __restrict__ counts2) {
  int idx = blockIdx.x * 256 + threadIdx.x;  // 512*256 = 131072 total
  if (idx < 16384) {
    int c8 = idx;
    int pos = c8 & 63;
    int t   = (c8 >> 6) & 1;
    int g   = (c8 >> 7) & 3;
    int kk  = (c8 >> 9) & 7;
    int wid = (c8 >> 12) & 3;
    int n = g * 128 + wid * 32 + t * 16 + (pos >> 2);
    int k0 = kk * 32 + (pos & 3) * 8;
    const float* src = (k0 < 128) ? (W_ih + (size_t)n * 128 + k0)
                                  : (W_hh + (size_t)n * 128 + (k0 - 128));
    f32x4 a = *(const f32x4*)(src);
    f32x4 b = *(const f32x4*)(src + 4);
    short8 v;
    v[0] = (short)f2bfu(a[0]); v[1] = (short)f2bfu(a[1]);
    v[2] = (short)f2bfu(a[2]); v[3] = (short)f2bfu(a[3]);
    v[4] = (short)f2bfu(b[0]); v[5] = (short)f2bfu(b[1]);
    v[6] = (short)f2bfu(b[2]); v[7] = (short)f2bfu(b[3]);
    *(short8*)(Wcat + (size_t)c8 * 8) = v;
  }
  if (idx < 512) bcomb[idx] = b_ih[idx] + b_hh[idx];
  if (idx < NV) { counts[idx] = 0; counts2[idx] = 0; }
}

// ---- Phase 1 (main): partitioned scatter + fp16 conversion of [0, ecut) ----
// Edges with fp16 coverage (e < ecut) fill each vertex's bucket from the
// FRONT (counts); uncovered edges fill from the BACK at slot 63-pos
// (counts2). Front+back crossing needs deg>64: P ~ 1e-18. The x_e->fp16
// streaming conversion (NT reads; e<XCUT -> xh0 in the out buffer, else xh1
// in ws spare) is BW-bound and overlaps the atomic-bound scatter.
__global__ __launch_bounds__(256) void scatcon_kernel(
    const int* __restrict__ eid, const int* __restrict__ vid,
    int* __restrict__ counts, int* __restrict__ counts2,
    int* __restrict__ slots, const float* __restrict__ x_e,
    _Float16* __restrict__ xh0, _Float16* __restrict__ xh1, int ecut) {
  unsigned j = blockIdx.x * 256 + threadIdx.x;
  if (j < NNZN) {
    int v = vid[j];
    int e = eid[j];
    if (e < ecut) {
      int pos = atomicAdd(&counts[v], 1);
      if (pos < SLOT_CAP) slots[(size_t)v * SLOT_CAP + pos] = e;
    } else {
      int pos = atomicAdd(&counts2[v], 1);
      if (pos < SLOT_CAP) slots[(size_t)v * SLOT_CAP + (SLOT_CAP - 1 - pos)] = e;
    }
  }
  const unsigned NU = (unsigned)ecut * 16u;  // 8-float units
  for (unsigned u = j; u < NU; u += SC_BLOCKS * 256u) {
    unsigned row = u >> 4;
    unsigned c8 = u & 15u;
    f32x4 a = __builtin_nontemporal_load((const f32x4*)(x_e + (size_t)u * 8));
    f32x4 b = __builtin_nontemporal_load((const f32x4*)(x_e + (size_t)u * 8 + 4));
    h8v h;
    h[0] = (_Float16)a[0]; h[1] = (_Float16)a[1];
    h[2] = (_Float16)a[2]; h[3] = (_Float16)a[3];
    h[4] = (_Float16)b[0]; h[5] = (_Float16)b[1];
    h[6] = (_Float16)b[2]; h[7] = (_Float16)b[3];
    _Float16* dst = (row < XCUT) ? (xh0 + (size_t)row * D)
                                 : (xh1 + (size_t)(row - XCUT) * D);
    *(h8v*)(dst + c8 * 8) = h;
  }
}

// ---------------- Phase 1 (fallback, small ws): plain scatter ---------------
__global__ __launch_bounds__(256) void scatter_direct_kernel(
    const int* __restrict__ eid, const int* __restrict__ vid,
    int* __restrict__ counts, int* __restrict__ slots) {
  int j = blockIdx.x * 256 + threadIdx.x;
  if (j < NNZN) {
    int v = vid[j];
    int pos = atomicAdd(&counts[v], 1);
    if (pos < SLOT_CAP) slots[(size_t)v * SLOT_CAP + pos] = eid[j];
  }
}

// ---------------- Phase 2 (main): mixed fp16/f32 gather ----------------
// One wave per vertex, grp = lane>>4 (4 edge groups), p16 = lane&15 (features
// [p16*8, p16*8+8)). Front loop: fp16 rows, one dwordx4 wave-load covers FOUR
// 256B rows -> 2 lines/edge (half of f32). Back loop: f32 rows read as two
// f32x4 per lane in the SAME lane layout -> results merge in registers.
// Masked volleys (clamped index -> cache-hit dup load, ternary-zeroed), no
// serial tails anywhere.
__global__ __launch_bounds__(256, 4) void gather_mixed_kernel(
    const float* __restrict__ x_e, const _Float16* __restrict__ xh0,
    const _Float16* __restrict__ xh1, const int* __restrict__ counts,
    const int* __restrict__ counts2, const int* __restrict__ slots,
    unsigned short* __restrict__ msgws) {
  __shared__ int slds[4][SLOT_CAP];
  const int tid = threadIdx.x;
  const int wid = tid >> 6;
  const int lane = tid & 63;
  const int v = blockIdx.x * 4 + wid;  // NV % 4 == 0
  const int grp = lane >> 4;
  const int p16 = lane & 15;
  int degf = counts[v];   degf = degf > SLOT_CAP ? SLOT_CAP : degf;
  int degb = counts2[v];  degb = degb > SLOT_CAP ? SLOT_CAP : degb;
  slds[wid][lane] = slots[(size_t)v * SLOT_CAP + lane];
  const int* row_ids = slds[wid];

  f32x8 A0 = {0.f,0.f,0.f,0.f,0.f,0.f,0.f,0.f};
  f32x8 A1 = A0, A2 = A0, A3 = A0;
  const f32x8 Z = A0;

  // ---- front: fp16 rows ----
  const int nfull = degf >> 5;
  const int rem = degf & 31;
#pragma unroll 1
  for (int c = 0; c < nfull; ++c) {
    int b = c * 32 + grp;
    h8v t0, t1, t2, t3, t4, t5, t6, t7;
#pragma unroll
    for (int k = 0; k < 8; ++k) {
      int e = row_ids[b + 4 * k];
      const _Float16* p = (e < XCUT) ? (xh0 + (size_t)e * D)
                                     : (xh1 + (size_t)(e - XCUT) * D);
      h8v t = *(const h8v*)(p + p16 * 8);
      switch (k) {
        case 0: t0 = t; break; case 1: t1 = t; break;
        case 2: t2 = t; break; case 3: t3 = t; break;
        case 4: t4 = t; break; case 5: t5 = t; break;
        case 6: t6 = t; break; case 7: t7 = t; break;
      }
    }
    A0 += h2f8(t0); A1 += h2f8(t1); A2 += h2f8(t2); A3 += h2f8(t3);
    A0 += h2f8(t4); A1 += h2f8(t5); A2 += h2f8(t6); A3 += h2f8(t7);
  }
  if (rem) {  // one masked 32-edge volley
    int b = nfull * 32 + grp;
    h8v t[8];
    int valid[8];
#pragma unroll
    for (int k = 0; k < 8; ++k) {
      int i = b + 4 * k;
      valid[k] = (i < degf);
      int e = row_ids[valid[k] ? i : 0];
      const _Float16* p = (e < XCUT) ? (xh0 + (size_t)e * D)
                                     : (xh1 + (size_t)(e - XCUT) * D);
      t[k] = *(const h8v*)(p + p16 * 8);
    }
    A0 += valid[0] ? h2f8(t[0]) : Z;
    A1 += valid[1] ? h2f8(t[1]) : Z;
    A2 += valid[2] ? h2f8(t[2]) : Z;
    A3 += valid[3] ? h2f8(t[3]) : Z;
    A0 += valid[4] ? h2f8(t[4]) : Z;
    A1 += valid[5] ? h2f8(t[5]) : Z;
    A2 += valid[6] ? h2f8(t[6]) : Z;
    A3 += valid[7] ? h2f8(t[7]) : Z;
  }

  // ---- back: f32 rows, slots filled from index 63 downward ----
  if (degb) {
    f32x4 bl0 = {0.f,0.f,0.f,0.f}, bh0 = bl0, bl1 = bl0, bh1 = bl0;
    const f32x4 z4 = bl0;
    const int nvb = (degb + 7) >> 3;  // masked 8-edge volleys (2 per grp)
#pragma unroll 1
    for (int c = 0; c < nvb; ++c) {
      int b = c * 8 + grp;
      int i0 = b, i1 = b + 4;
      int e0 = row_ids[SLOT_CAP - 1 - (i0 < degb ? i0 : 0)];
      int e1 = row_ids[SLOT_CAP - 1 - (i1 < degb ? i1 : 0)];
      const float* p0 = x_e + (size_t)e0 * D + p16 * 8;
      const float* p1 = x_e + (size_t)e1 * D + p16 * 8;
      f32x4 l0 = *(const f32x4*)(p0);
      f32x4 h0 = *(const f32x4*)(p0 + 4);
      f32x4 l1 = *(const f32x4*)(p1);
      f32x4 h1 = *(const f32x4*)(p1 + 4);
      bl0 += (i0 < degb) ? l0 : z4;
      bh0 += (i0 < degb) ? h0 : z4;
      bl1 += (i1 < degb) ? l1 : z4;
      bh1 += (i1 < degb) ? h1 : z4;
    }
    bl0 += bl1;
    bh0 += bh1;
#pragma unroll
    for (int k = 0; k < 4; ++k) {
      A0[k] += bl0[k];
      A0[4 + k] += bh0[k];
    }
  }

  A0 += A1;
  A2 += A3;
  A0 += A2;
  // reduce across the 4 edge groups (lane^32, lane^16)
#pragma unroll
  for (int f = 0; f < 8; ++f) {
    float x = A0[f];
    x += __shfl_xor(x, 32);
    x += __shfl_xor(x, 16);
    A0[f] = x;
  }
  if (lane < 16) {
    short8 p;
#pragma unroll
    for (int f = 0; f < 8; ++f) p[f] = (short)f2bfu(A0[f]);
    *(short8*)(msgws + (size_t)v * D + p16 * 8) = p;
  }
}

// ---------------- Phase 2 (fallback): f32 gather (R7 structure) -------------
__global__ __launch_bounds__(256, 4) void gather_kernel(
    const float* __restrict__ x_e, const int* __restrict__ counts,
    const int* __restrict__ slots, char* __restrict__ msgb) {
  __shared__ int slds[4][SLOT_CAP];
  const int tid = threadIdx.x;
  const int wid = tid >> 6;
  const int lane = tid & 63;
  const int v = blockIdx.x * 4 + wid;
  const int half = lane >> 5;
  const int pos = lane & 31;
  int deg = counts[v];
  deg = deg > SLOT_CAP ? SLOT_CAP : deg;
  slds[wid][lane] = slots[(size_t)v * SLOT_CAP + lane];
  const int* row_ids = slds[wid];

  f32x4 a0 = {0.f, 0.f, 0.f, 0.f}, a1 = a0, a2 = a0, a3 = a0;
  const int nfull = deg >> 4;
  const int rem = deg & 15;
#pragma unroll 1
  for (int c = 0; c < nfull; ++c) {
    int b = c * 16 + half;
    int e0 = row_ids[b];      int e1 = row_ids[b + 2];
    int e2 = row_ids[b + 4];  int e3 = row_ids[b + 6];
    int e4 = row_ids[b + 8];  int e5 = row_ids[b + 10];
    int e6 = row_ids[b + 12]; int e7 = row_ids[b + 14];
    a0 += *(const f32x4*)(x_e + (size_t)e0 * D + pos * 4);
    a1 += *(const f32x4*)(x_e + (size_t)e1 * D + pos * 4);
    a2 += *(const f32x4*)(x_e + (size_t)e2 * D + pos * 4);
    a3 += *(const f32x4*)(x_e + (size_t)e3 * D + pos * 4);
    a0 += *(const f32x4*)(x_e + (size_t)e4 * D + pos * 4);
    a1 += *(const f32x4*)(x_e + (size_t)e5 * D + pos * 4);
    a2 += *(const f32x4*)(x_e + (size_t)e6 * D + pos * 4);
    a3 += *(const f32x4*)(x_e + (size_t)e7 * D + pos * 4);
  }
  if (rem) {
    int b = nfull * 16 + half;
    f32x4 z = {0.f, 0.f, 0.f, 0.f};
    int i0 = b,      i1 = b + 2,  i2 = b + 4,  i3 = b + 6;
    int i4 = b + 8,  i5 = b + 10, i6 = b + 12, i7 = b + 14;
    int e0 = row_ids[i0 < deg ? i0 : 0];
    int e1 = row_ids[i1 < deg ? i1 : 0];
    int e2 = row_ids[i2 < deg ? i2 : 0];
    int e3 = row_ids[i3 < deg ? i3 : 0];
    int e4 = row_ids[i4 < deg ? i4 : 0];
    int e5 = row_ids[i5 < deg ? i5 : 0];
    int e6 = row_ids[i6 < deg ? i6 : 0];
    int e7 = row_ids[i7 < deg ? i7 : 0];
    f32x4 t0 = *(const f32x4*)(x_e + (size_t)e0 * D + pos * 4);
    f32x4 t1 = *(const f32x4*)(x_e + (size_t)e1 * D + pos * 4);
    f32x4 t2 = *(const f32x4*)(x_e + (size_t)e2 * D + pos * 4);
    f32x4 t3 = *(const f32x4*)(x_e + (size_t)e3 * D + pos * 4);
    f32x4 t4 = *(const f32x4*)(x_e + (size_t)e4 * D + pos * 4);
    f32x4 t5 = *(const f32x4*)(x_e + (size_t)e5 * D + pos * 4);
    f32x4 t6 = *(const f32x4*)(x_e + (size_t)e6 * D + pos * 4);
    f32x4 t7 = *(const f32x4*)(x_e + (size_t)e7 * D + pos * 4);
    a0 += (i0 < deg) ? t0 : z;
    a1 += (i1 < deg) ? t1 : z;
    a2 += (i2 < deg) ? t2 : z;
    a3 += (i3 < deg) ? t3 : z;
    a0 += (i4 < deg) ? t4 : z;
    a1 += (i5 < deg) ? t5 : z;
    a2 += (i6 < deg) ? t6 : z;
    a3 += (i7 < deg) ? t7 : z;
  }
  a0 += a1;
  a2 += a3;
  a0 += a2;
  f32x4 b;
  b[0] = __shfl_xor(a0[0], 32);
  b[1] = __shfl_xor(a0[1], 32);
  b[2] = __shfl_xor(a0[2], 32);
  b[3] = __shfl_xor(a0[3], 32);
  a0 += b;
  if (half == 0) {
    s16x4 p;
    p[0] = (short)f2bfu(a0[0]);
    p[1] = (short)f2bfu(a0[1]);
    p[2] = (short)f2bfu(a0[2]);
    p[3] = (short)f2bfu(a0[3]);
    *(s16x4*)(msgb + (size_t)v * 512 + pos * 8) = p;
  }
}

// ---------------- Phase 3: GEMM + LSTM cell ----------------
// Block = 256 threads (4 waves), 32 vertices. msg source parameterized:
// main path = contiguous 256B rows in ws; fallback = 512B-strided out_c rows.
__global__ __launch_bounds__(256) void lstm_kernel(
    const char* __restrict__ msgb, int msg_stride,
    const float* __restrict__ h_v, const float* __restrict__ c_v,
    const short* __restrict__ Wcat, const float* __restrict__ bcomb,
    float* __restrict__ out) {
  __shared__ char Atile[32 * 256 * 2];  // 16 KB
  const int tid = threadIdx.x;
  const int vbase = blockIdx.x * 32;

#pragma unroll
  for (int i = 0; i < 4; ++i) {
    int cid = tid + i * 256;  // 0..1023 = 32 rows x 32 16B-chunks
    int row = cid >> 5;
    int c = cid & 31;
    short8 v;
    if (c < 16) {
      v = *(const short8*)(msgb + (size_t)(vbase + row) * msg_stride + c * 16);
    } else {
      const float* src = h_v + (size_t)(vbase + row) * D + (c - 16) * 8;
      f32x4 a = *(const f32x4*)(src);
      f32x4 b = *(const f32x4*)(src + 4);
      v[0] = (short)f2bfu(a[0]); v[1] = (short)f2bfu(a[1]);
      v[2] = (short)f2bfu(a[2]); v[3] = (short)f2bfu(a[3]);
      v[4] = (short)f2bfu(b[0]); v[5] = (short)f2bfu(b[1]);
      v[6] = (short)f2bfu(b[2]); v[7] = (short)f2bfu(b[3]);
    }
    int byteoff = (row * 512 + c * 16) ^ ((row & 7) << 4);
    *(short8*)(Atile + byteoff) = v;
  }
  __syncthreads();

  const int wid = tid >> 6;
  const int lane = tid & 63;
  const int l16 = lane & 15;
  const int lhi = lane >> 4;  // 0..3

  f32x4 acc[2][4][2] = {};  // [m-tile][gate][d-subtile]

#pragma unroll
  for (int kk = 0; kk < 8; ++kk) {
    short8 afrag[2];
#pragma unroll
    for (int m = 0; m < 2; ++m) {
      int row = m * 16 + l16;
      int byteoff = (row * 512 + kk * 64 + lhi * 16) ^ ((row & 7) << 4);
      afrag[m] = *(const short8*)(Atile + byteoff);
    }
#pragma unroll
    for (int g = 0; g < 4; ++g) {
#pragma unroll
      for (int t = 0; t < 2; ++t) {
        size_t boff = (size_t)(wid * 64 + kk * 8 + g * 2 + t) * 1024
                    + (size_t)(l16 * 4 + lhi) * 16;
        short8 bfrag = *(const short8*)((const char*)Wcat + boff);
        acc[0][g][t] = __builtin_amdgcn_mfma_f32_16x16x32_bf16(afrag[0], bfrag, acc[0][g][t], 0, 0, 0);
        acc[1][g][t] = __builtin_amdgcn_mfma_f32_16x16x32_bf16(afrag[1], bfrag, acc[1][g][t], 0, 0, 0);
      }
    }
  }

  float* out_h = out;
  float* out_c = out + (size_t)NV * D;
#pragma unroll
  for (int m = 0; m < 2; ++m) {
#pragma unroll
    for (int t = 0; t < 2; ++t) {
      int d = wid * 32 + t * 16 + l16;
      float bi = bcomb[d];
      float bf = bcomb[128 + d];
      float bg = bcomb[256 + d];
      float bo = bcomb[384 + d];
#pragma unroll
      for (int r = 0; r < 4; ++r) {
        int v = vbase + m * 16 + lhi * 4 + r;
        float gi = acc[m][0][t][r] + bi;
        float gf = acc[m][1][t][r] + bf;
        float gg = acc[m][2][t][r] + bg;
        float go = acc[m][3][t][r] + bo;
        float ii = fsigmoid(gi);
        float ff = fsigmoid(gf);
        float g_ = ftanh(gg);
        float oo = fsigmoid(go);
        float cv = c_v[(size_t)v * D + d];
        float cn = ff * cv + ii * g_;
        float hn = oo * ftanh(cn);
        out_h[(size_t)v * D + d] = hn;
        out_c[(size_t)v * D + d] = cn;
      }
    }
  }
}

extern "C" void kernel_launch(void* const* d_in, const int* in_sizes, int n_in,
                              void* d_out, int out_size, void* d_ws, size_t ws_size,
                              hipStream_t stream) {
  const float* x_e  = (const float*)d_in[0];
  const float* h_v  = (const float*)d_in[1];
  const float* c_v  = (const float*)d_in[2];
  const float* W_ih = (const float*)d_in[3];
  const float* W_hh = (const float*)d_in[4];
  const float* b_ih = (const float*)d_in[5];
  const float* b_hh = (const float*)d_in[6];
  const int* eid    = (const int*)d_in[7];
  const int* vid    = (const int*)d_in[8];
  // d_in[9] = v_batch: unused by the reference computation.
  float* out = (float*)d_out;

  // ws layout (main): Wcat | bcomb | counts | counts2 | slots | msgws | xh1
  char* w = (char*)d_ws;
  short* Wcat   = (short*)w;                w += 512 * 256 * sizeof(short);
  float* bcomb  = (float*)w;                w += 512 * sizeof(float);
  int* counts   = (int*)w;                  w += NV * sizeof(int);
  int* counts2  = (int*)w;                  w += NV * sizeof(int);
  int* slots    = (int*)w;                  w += (size_t)NV * SLOT_CAP * sizeof(int);
  unsigned short* msgws = (unsigned short*)w;  w += (size_t)NV * D * sizeof(unsigned short);
  _Float16* xh1 = (_Float16*)w;

  const size_t base_end = 512 * 256 * sizeof(short) + 512 * sizeof(float)
                        + 2 * (size_t)NV * sizeof(int)
                        + (size_t)NV * SLOT_CAP * sizeof(int)
                        + (size_t)NV * D * sizeof(unsigned short);  // ~52.3 MB

  if (ws_size >= base_end) {
    // fp16 rows for edges < XCUT live in the (dead-until-lstm) out buffer:
    // XCUT*256B == out_size exactly. ws spare extends coverage to ecut.
    _Float16* xh0 = (_Float16*)out;
    size_t spare = ws_size - base_end;
    size_t extra = spare / 256;
    if (extra > (size_t)(NE - XCUT)) extra = NE - XCUT;
    int ecut = XCUT + (int)(extra & ~(size_t)31);
    wconv_kernel<<<512, 256, 0, stream>>>(W_ih, W_hh, b_ih, b_hh, Wcat, bcomb,
                                          counts, counts2);
    scatcon_kernel<<<SC_BLOCKS, 256, 0, stream>>>(eid, vid, counts, counts2,
                                                  slots, x_e, xh0, xh1, ecut);
    gather_mixed_kernel<<<NV / 4, 256, 0, stream>>>(x_e, xh0, xh1, counts,
                                                    counts2, slots, msgws);
    lstm_kernel<<<NV / 32, 256, 0, stream>>>((const char*)msgws, 256, h_v, c_v,
                                             Wcat, bcomb, out);
  } else {
    // Fallback (R7 path): msg bf16 in the low 256B of each 512B out_c row.
    char* msgb = (char*)(out + (size_t)NV * D);
    wconv_kernel<<<512, 256, 0, stream>>>(W_ih, W_hh, b_ih, b_hh, Wcat, bcomb,
                                          counts, counts2);
    scatter_direct_kernel<<<(NNZN + 255) / 256, 256, 0, stream>>>(eid, vid,
                                                                  counts, slots);
    gather_kernel<<<NV / 4, 256, 0, stream>>>(x_e, counts, slots, msgb);
    lstm_kernel<<<NV / 32, 256, 0, stream>>>(msgb, 512, h_v, c_v, Wcat, bcomb,
                                             out);
  }
}

// Round 10
// 402.977 us; speedup vs baseline: 1.0401x; 1.0060x over previous
//
#include <hip/hip_runtime.h>
#include <hip/hip_bf16.h>

#define NE 800000
#define NV 100000
#define NNZN 1600000
#define D 128
#define SLOT_CAP 64    // slots per vertex; P(Poisson(16) > 63) ~ 1e-18, clamped
#define XH0_CAP 200000 // fp16 rows hosted in out_h: 200K * 256B == out_h size
#define SC_BLOCKS 8192

typedef short short8 __attribute__((ext_vector_type(8)));
typedef short s16x4 __attribute__((ext_vector_type(4)));
typedef float f32x4 __attribute__((ext_vector_type(4)));
typedef float f32x8 __attribute__((ext_vector_type(8)));
typedef _Float16 h8v __attribute__((ext_vector_type(8)));

__device__ __forceinline__ unsigned short f2bfu(float f) {
  union { float f; unsigned u; } x;
  x.f = f;
  unsigned u = x.u;
  u += ((u >> 16) & 1u) + 0x7FFFu;  // round-to-nearest-even
  return (unsigned short)(u >> 16);
}

__device__ __forceinline__ float fsigmoid(float x) {
  return 1.0f / (1.0f + __expf(-x));
}
__device__ __forceinline__ float ftanh(float x) {
  return 2.0f / (1.0f + __expf(-2.0f * x)) - 1.0f;
}

__device__ __forceinline__ f32x8 h2f8(h8v h) {
  f32x8 r;
#pragma unroll
  for (int k = 0; k < 8; ++k) r[k] = (float)h[k];
  return r;
}

// ---------------- Phase 0: W/bias prep + counters zeroing ----------------
// Wcat layout: 16B chunks indexed c8 = (((wid*8+kk)*4+g)*2+t)*64 + (l16*4+lhi)
// so each MFMA B-fragment wave-load in the lstm kernel is one contiguous
// 1 KB segment.
__global__ __launch_bounds__(256) void wconv_kernel(
    const float* __restrict__ W_ih, const float* __restrict__ W_hh,
    const float* __restrict__ b_ih, const float* __restrict__ b_hh,
    short* __restrict__ Wcat, float* __restrict__ bcomb,
    int* __restrict__ counts, int* __restrict__ counts2) {
  int idx = blockIdx.x * 256 + threadIdx.x;  // 512*256 = 131072 total
  if (idx < 16384) {
    int c8 = idx;
    int pos = c8 & 63;
    int t   = (c8 >> 6) & 1;
    int g   = (c8 >> 7) & 3;
    int kk  = (c8 >> 9) & 7;
    int wid = (c8 >> 12) & 3;
    int n = g * 128 + wid * 32 + t * 16 + (pos >> 2);
    int k0 = kk * 32 + (pos & 3) * 8;
    const float* src = (k0 < 128) ? (W_ih + (size_t)n * 128 + k0)
                                  : (W_hh + (size_t)n * 128 + (k0 - 128));
    f32x4 a = *(const f32x4*)(src);
    f32x4 b = *(const f32x4*)(src + 4);
    short8 v;
    v[0] = (short)f2bfu(a[0]); v[1] = (short)f2bfu(a[1]);
    v[2] = (short)f2bfu(a[2]); v[3] = (short)f2bfu(a[3]);
    v[4] = (short)f2bfu(b[0]); v[5] = (short)f2bfu(b[1]);
    v[6] = (short)f2bfu(b[2]); v[7] = (short)f2bfu(b[3]);
    *(short8*)(Wcat + (size_t)c8 * 8) = v;
  }
  if (idx < 512) bcomb[idx] = b_ih[idx] + b_hh[idx];
  if (idx < NV) { counts[idx] = 0; counts2[idx] = 0; }
}

// ---- Phase 1 (main): partitioned scatter + fp16 conversion of [0, ecut) ----
// Edges with fp16 coverage (e < ecut) fill each vertex's bucket from the
// FRONT (counts); uncovered edges fill from the BACK at slot 63-pos
// (counts2). Front+back crossing needs deg>64: P ~ 1e-18. Conversion dst:
// rows < XH0_CAP -> xh0 (the out_h region, consumed by gather before lstm
// overwrites it); rows >= XH0_CAP -> xh1 (ws spare). NT reads; streaming
// conversion (BW-bound) overlaps the atomic-bound scatter across blocks.
__global__ __launch_bounds__(256) void scatcon_kernel(
    const int* __restrict__ eid, const int* __restrict__ vid,
    int* __restrict__ counts, int* __restrict__ counts2,
    int* __restrict__ slots, const float* __restrict__ x_e,
    _Float16* __restrict__ xh0, _Float16* __restrict__ xh1, int ecut) {
  unsigned j = blockIdx.x * 256 + threadIdx.x;
  if (j < NNZN) {
    int v = vid[j];
    int e = eid[j];
    if (e < ecut) {
      int pos = atomicAdd(&counts[v], 1);
      if (pos < SLOT_CAP) slots[(size_t)v * SLOT_CAP + pos] = e;
    } else {
      int pos = atomicAdd(&counts2[v], 1);
      if (pos < SLOT_CAP) slots[(size_t)v * SLOT_CAP + (SLOT_CAP - 1 - pos)] = e;
    }
  }
  const unsigned NU = (unsigned)ecut * 16u;  // 8-float units
  for (unsigned u = j; u < NU; u += SC_BLOCKS * 256u) {
    unsigned row = u >> 4;
    unsigned c8 = u & 15u;
    f32x4 a = __builtin_nontemporal_load((const f32x4*)(x_e + (size_t)u * 8));
    f32x4 b = __builtin_nontemporal_load((const f32x4*)(x_e + (size_t)u * 8 + 4));
    h8v h;
    h[0] = (_Float16)a[0]; h[1] = (_Float16)a[1];
    h[2] = (_Float16)a[2]; h[3] = (_Float16)a[3];
    h[4] = (_Float16)b[0]; h[5] = (_Float16)b[1];
    h[6] = (_Float16)b[2]; h[7] = (_Float16)b[3];
    _Float16* dst = (row < XH0_CAP) ? (xh0 + (size_t)row * D)
                                    : (xh1 + (size_t)(row - XH0_CAP) * D);
    *(h8v*)(dst + c8 * 8) = h;
  }
}

// ---------------- Phase 1 (fallback, tiny ws): plain scatter ---------------
__global__ __launch_bounds__(256) void scatter_direct_kernel(
    const int* __restrict__ eid, const int* __restrict__ vid,
    int* __restrict__ counts, int* __restrict__ slots) {
  int j = blockIdx.x * 256 + threadIdx.x;
  if (j < NNZN) {
    int v = vid[j];
    int pos = atomicAdd(&counts[v], 1);
    if (pos < SLOT_CAP) slots[(size_t)v * SLOT_CAP + pos] = eid[j];
  }
}

// ---------------- Phase 2 (main): mixed fp16/f32 gather ----------------
// One wave per vertex, grp = lane>>4 (4 edge groups), p16 = lane&15 (features
// [p16*8, p16*8+8)). Front loop: fp16 rows, one dwordx4 wave-load covers FOUR
// 256B rows -> 2 lines/edge (half of f32). Back loop: f32 rows in the SAME
// lane layout -> results merge in registers. Masked volleys (clamped index ->
// cache-hit dup load, ternary-zeroed), no serial tails anywhere.
// msg bf16 goes to the low 256B of each 512B out_c row.
__global__ __launch_bounds__(256, 4) void gather_mixed_kernel(
    const float* __restrict__ x_e, const _Float16* __restrict__ xh0,
    const _Float16* __restrict__ xh1, const int* __restrict__ counts,
    const int* __restrict__ counts2, const int* __restrict__ slots,
    char* __restrict__ msgb) {
  __shared__ int slds[4][SLOT_CAP];
  const int tid = threadIdx.x;
  const int wid = tid >> 6;
  const int lane = tid & 63;
  const int v = blockIdx.x * 4 + wid;  // NV % 4 == 0
  const int grp = lane >> 4;
  const int p16 = lane & 15;
  int degf = counts[v];   degf = degf > SLOT_CAP ? SLOT_CAP : degf;
  int degb = counts2[v];  degb = degb > SLOT_CAP ? SLOT_CAP : degb;
  slds[wid][lane] = slots[(size_t)v * SLOT_CAP + lane];
  const int* row_ids = slds[wid];

  f32x8 A0 = {0.f,0.f,0.f,0.f,0.f,0.f,0.f,0.f};
  f32x8 A1 = A0, A2 = A0, A3 = A0;
  const f32x8 Z = A0;

  // ---- front: fp16 rows ----
  const int nfull = degf >> 5;
  const int rem = degf & 31;
#pragma unroll 1
  for (int c = 0; c < nfull; ++c) {
    int b = c * 32 + grp;
    h8v t0, t1, t2, t3, t4, t5, t6, t7;
#pragma unroll
    for (int k = 0; k < 8; ++k) {
      int e = row_ids[b + 4 * k];
      const _Float16* p = (e < XH0_CAP) ? (xh0 + (size_t)e * D)
                                        : (xh1 + (size_t)(e - XH0_CAP) * D);
      h8v t = *(const h8v*)(p + p16 * 8);
      switch (k) {
        case 0: t0 = t; break; case 1: t1 = t; break;
        case 2: t2 = t; break; case 3: t3 = t; break;
        case 4: t4 = t; break; case 5: t5 = t; break;
        case 6: t6 = t; break; case 7: t7 = t; break;
      }
    }
    A0 += h2f8(t0); A1 += h2f8(t1); A2 += h2f8(t2); A3 += h2f8(t3);
    A0 += h2f8(t4); A1 += h2f8(t5); A2 += h2f8(t6); A3 += h2f8(t7);
  }
  if (rem) {  // one masked 32-edge volley
    int b = nfull * 32 + grp;
    h8v t[8];
    int valid[8];
#pragma unroll
    for (int k = 0; k < 8; ++k) {
      int i = b + 4 * k;
      valid[k] = (i < degf);
      int e = row_ids[valid[k] ? i : 0];
      const _Float16* p = (e < XH0_CAP) ? (xh0 + (size_t)e * D)
                                        : (xh1 + (size_t)(e - XH0_CAP) * D);
      t[k] = *(const h8v*)(p + p16 * 8);
    }
    A0 += valid[0] ? h2f8(t[0]) : Z;
    A1 += valid[1] ? h2f8(t[1]) : Z;
    A2 += valid[2] ? h2f8(t[2]) : Z;
    A3 += valid[3] ? h2f8(t[3]) : Z;
    A0 += valid[4] ? h2f8(t[4]) : Z;
    A1 += valid[5] ? h2f8(t[5]) : Z;
    A2 += valid[6] ? h2f8(t[6]) : Z;
    A3 += valid[7] ? h2f8(t[7]) : Z;
  }

  // ---- back: f32 rows, slots filled from index 63 downward ----
  if (degb) {
    f32x4 bl0 = {0.f,0.f,0.f,0.f}, bh0 = bl0, bl1 = bl0, bh1 = bl0;
    const f32x4 z4 = bl0;
    const int nvb = (degb + 7) >> 3;  // masked 8-edge volleys (2 per grp)
#pragma unroll 1
    for (int c = 0; c < nvb; ++c) {
      int b = c * 8 + grp;
      int i0 = b, i1 = b + 4;
      int e0 = row_ids[SLOT_CAP - 1 - (i0 < degb ? i0 : 0)];
      int e1 = row_ids[SLOT_CAP - 1 - (i1 < degb ? i1 : 0)];
      const float* p0 = x_e + (size_t)e0 * D + p16 * 8;
      const float* p1 = x_e + (size_t)e1 * D + p16 * 8;
      f32x4 l0 = *(const f32x4*)(p0);
      f32x4 h0 = *(const f32x4*)(p0 + 4);
      f32x4 l1 = *(const f32x4*)(p1);
      f32x4 h1 = *(const f32x4*)(p1 + 4);
      bl0 += (i0 < degb) ? l0 : z4;
      bh0 += (i0 < degb) ? h0 : z4;
      bl1 += (i1 < degb) ? l1 : z4;
      bh1 += (i1 < degb) ? h1 : z4;
    }
    bl0 += bl1;
    bh0 += bh1;
#pragma unroll
    for (int k = 0; k < 4; ++k) {
      A0[k] += bl0[k];
      A0[4 + k] += bh0[k];
    }
  }

  A0 += A1;
  A2 += A3;
  A0 += A2;
  // reduce across the 4 edge groups (lane^32, lane^16)
#pragma unroll
  for (int f = 0; f < 8; ++f) {
    float x = A0[f];
    x += __shfl_xor(x, 32);
    x += __shfl_xor(x, 16);
    A0[f] = x;
  }
  if (lane < 16) {
    short8 p;
#pragma unroll
    for (int f = 0; f < 8; ++f) p[f] = (short)f2bfu(A0[f]);
    *(short8*)(msgb + (size_t)v * 512 + p16 * 16) = p;
  }
}

// ---------------- Phase 2 (fallback): f32 gather (R7 structure) -------------
__global__ __launch_bounds__(256, 4) void gather_kernel(
    const float* __restrict__ x_e, const int* __restrict__ counts,
    const int* __restrict__ slots, char* __restrict__ msgb) {
  __shared__ int slds[4][SLOT_CAP];
  const int tid = threadIdx.x;
  const int wid = tid >> 6;
  const int lane = tid & 63;
  const int v = blockIdx.x * 4 + wid;
  const int half = lane >> 5;
  const int pos = lane & 31;
  int deg = counts[v];
  deg = deg > SLOT_CAP ? SLOT_CAP : deg;
  slds[wid][lane] = slots[(size_t)v * SLOT_CAP + lane];
  const int* row_ids = slds[wid];

  f32x4 a0 = {0.f, 0.f, 0.f, 0.f}, a1 = a0, a2 = a0, a3 = a0;
  const int nfull = deg >> 4;
  const int rem = deg & 15;
#pragma unroll 1
  for (int c = 0; c < nfull; ++c) {
    int b = c * 16 + half;
    int e0 = row_ids[b];      int e1 = row_ids[b + 2];
    int e2 = row_ids[b + 4];  int e3 = row_ids[b + 6];
    int e4 = row_ids[b + 8];  int e5 = row_ids[b + 10];
    int e6 = row_ids[b + 12]; int e7 = row_ids[b + 14];
    a0 += *(const f32x4*)(x_e + (size_t)e0 * D + pos * 4);
    a1 += *(const f32x4*)(x_e + (size_t)e1 * D + pos * 4);
    a2 += *(const f32x4*)(x_e + (size_t)e2 * D + pos * 4);
    a3 += *(const f32x4*)(x_e + (size_t)e3 * D + pos * 4);
    a0 += *(const f32x4*)(x_e + (size_t)e4 * D + pos * 4);
    a1 += *(const f32x4*)(x_e + (size_t)e5 * D + pos * 4);
    a2 += *(const f32x4*)(x_e + (size_t)e6 * D + pos * 4);
    a3 += *(const f32x4*)(x_e + (size_t)e7 * D + pos * 4);
  }
  if (rem) {
    int b = nfull * 16 + half;
    f32x4 z = {0.f, 0.f, 0.f, 0.f};
    int i0 = b,      i1 = b + 2,  i2 = b + 4,  i3 = b + 6;
    int i4 = b + 8,  i5 = b + 10, i6 = b + 12, i7 = b + 14;
    int e0 = row_ids[i0 < deg ? i0 : 0];
    int e1 = row_ids[i1 < deg ? i1 : 0];
    int e2 = row_ids[i2 < deg ? i2 : 0];
    int e3 = row_ids[i3 < deg ? i3 : 0];
    int e4 = row_ids[i4 < deg ? i4 : 0];
    int e5 = row_ids[i5 < deg ? i5 : 0];
    int e6 = row_ids[i6 < deg ? i6 : 0];
    int e7 = row_ids[i7 < deg ? i7 : 0];
    f32x4 t0 = *(const f32x4*)(x_e + (size_t)e0 * D + pos * 4);
    f32x4 t1 = *(const f32x4*)(x_e + (size_t)e1 * D + pos * 4);
    f32x4 t2 = *(const f32x4*)(x_e + (size_t)e2 * D + pos * 4);
    f32x4 t3 = *(const f32x4*)(x_e + (size_t)e3 * D + pos * 4);
    f32x4 t4 = *(const f32x4*)(x_e + (size_t)e4 * D + pos * 4);
    f32x4 t5 = *(const f32x4*)(x_e + (size_t)e5 * D + pos * 4);
    f32x4 t6 = *(const f32x4*)(x_e + (size_t)e6 * D + pos * 4);
    f32x4 t7 = *(const f32x4*)(x_e + (size_t)e7 * D + pos * 4);
    a0 += (i0 < deg) ? t0 : z;
    a1 += (i1 < deg) ? t1 : z;
    a2 += (i2 < deg) ? t2 : z;
    a3 += (i3 < deg) ? t3 : z;
    a0 += (i4 < deg) ? t4 : z;
    a1 += (i5 < deg) ? t5 : z;
    a2 += (i6 < deg) ? t6 : z;
    a3 += (i7 < deg) ? t7 : z;
  }
  a0 += a1;
  a2 += a3;
  a0 += a2;
  f32x4 b;
  b[0] = __shfl_xor(a0[0], 32);
  b[1] = __shfl_xor(a0[1], 32);
  b[2] = __shfl_xor(a0[2], 32);
  b[3] = __shfl_xor(a0[3], 32);
  a0 += b;
  if (half == 0) {
    s16x4 p;
    p[0] = (short)f2bfu(a0[0]);
    p[1] = (short)f2bfu(a0[1]);
    p[2] = (short)f2bfu(a0[2]);
    p[3] = (short)f2bfu(a0[3]);
    *(s16x4*)(msgb + (size_t)v * 512 + pos * 8) = p;
  }
}

// ---------------- Phase 3: GEMM + LSTM cell ----------------
// Block = 256 threads (4 waves), 32 vertices.
// A tile: [32 rows][256 k] bf16 in LDS (XOR-swizzled, row stride 512B),
// cols 0..15 = msg (bf16, read from out_c rows this block will overwrite),
// cols 16..31 = h_v (bf16). Wave wid owns feature slice [wid*32, wid*32+32).
__global__ __launch_bounds__(256) void lstm_kernel(
    const char* __restrict__ msgb, const float* __restrict__ h_v,
    const float* __restrict__ c_v, const short* __restrict__ Wcat,
    const float* __restrict__ bcomb, float* __restrict__ out) {
  __shared__ char Atile[32 * 256 * 2];  // 16 KB
  const int tid = threadIdx.x;
  const int vbase = blockIdx.x * 32;

#pragma unroll
  for (int i = 0; i < 4; ++i) {
    int cid = tid + i * 256;  // 0..1023 = 32 rows x 32 16B-chunks
    int row = cid >> 5;
    int c = cid & 31;
    short8 v;
    if (c < 16) {
      v = *(const short8*)(msgb + (size_t)(vbase + row) * 512 + c * 16);
    } else {
      const float* src = h_v + (size_t)(vbase + row) * D + (c - 16) * 8;
      f32x4 a = *(const f32x4*)(src);
      f32x4 b = *(const f32x4*)(src + 4);
      v[0] = (short)f2bfu(a[0]); v[1] = (short)f2bfu(a[1]);
      v[2] = (short)f2bfu(a[2]); v[3] = (short)f2bfu(a[3]);
      v[4] = (short)f2bfu(b[0]); v[5] = (short)f2bfu(b[1]);
      v[6] = (short)f2bfu(b[2]); v[7] = (short)f2bfu(b[3]);
    }
    int byteoff = (row * 512 + c * 16) ^ ((row & 7) << 4);
    *(short8*)(Atile + byteoff) = v;
  }
  __syncthreads();

  const int wid = tid >> 6;
  const int lane = tid & 63;
  const int l16 = lane & 15;
  const int lhi = lane >> 4;  // 0..3

  f32x4 acc[2][4][2] = {};  // [m-tile][gate][d-subtile]

#pragma unroll
  for (int kk = 0; kk < 8; ++kk) {
    short8 afrag[2];
#pragma unroll
    for (int m = 0; m < 2; ++m) {
      int row = m * 16 + l16;
      int byteoff = (row * 512 + kk * 64 + lhi * 16) ^ ((row & 7) << 4);
      afrag[m] = *(const short8*)(Atile + byteoff);
    }
#pragma unroll
    for (int g = 0; g < 4; ++g) {
#pragma unroll
      for (int t = 0; t < 2; ++t) {
        // coalesced Wcat layout: contiguous 1KB per wave-load
        size_t boff = (size_t)(wid * 64 + kk * 8 + g * 2 + t) * 1024
                    + (size_t)(l16 * 4 + lhi) * 16;
        short8 bfrag = *(const short8*)((const char*)Wcat + boff);
        acc[0][g][t] = __builtin_amdgcn_mfma_f32_16x16x32_bf16(afrag[0], bfrag, acc[0][g][t], 0, 0, 0);
        acc[1][g][t] = __builtin_amdgcn_mfma_f32_16x16x32_bf16(afrag[1], bfrag, acc[1][g][t], 0, 0, 0);
      }
    }
  }

  float* out_h = out;
  float* out_c = out + (size_t)NV * D;
#pragma unroll
  for (int m = 0; m < 2; ++m) {
#pragma unroll
    for (int t = 0; t < 2; ++t) {
      int d = wid * 32 + t * 16 + l16;
      float bi = bcomb[d];
      float bf = bcomb[128 + d];
      float bg = bcomb[256 + d];
      float bo = bcomb[384 + d];
#pragma unroll
      for (int r = 0; r < 4; ++r) {
        int v = vbase + m * 16 + lhi * 4 + r;
        float gi = acc[m][0][t][r] + bi;
        float gf = acc[m][1][t][r] + bf;
        float gg = acc[m][2][t][r] + bg;
        float go = acc[m][3][t][r] + bo;
        float ii = fsigmoid(gi);
        float ff = fsigmoid(gf);
        float g_ = ftanh(gg);
        float oo = fsigmoid(go);
        float cv = c_v[(size_t)v * D + d];
        float cn = ff * cv + ii * g_;
        float hn = oo * ftanh(cn);
        out_h[(size_t)v * D + d] = hn;
        out_c[(size_t)v * D + d] = cn;
      }
    }
  }
}

extern "C" void kernel_launch(void* const* d_in, const int* in_sizes, int n_in,
                              void* d_out, int out_size, void* d_ws, size_t ws_size,
                              hipStream_t stream) {
  const float* x_e  = (const float*)d_in[0];
  const float* h_v  = (const float*)d_in[1];
  const float* c_v  = (const float*)d_in[2];
  const float* W_ih = (const float*)d_in[3];
  const float* W_hh = (const float*)d_in[4];
  const float* b_ih = (const float*)d_in[5];
  const float* b_hh = (const float*)d_in[6];
  const int* eid    = (const int*)d_in[7];
  const int* vid    = (const int*)d_in[8];
  // d_in[9] = v_batch: unused by the reference computation.
  float* out = (float*)d_out;

  // ws layout: Wcat | bcomb | counts | counts2 | slots | xh1 (spare)
  char* w = (char*)d_ws;
  short* Wcat   = (short*)w;                w += 512 * 256 * sizeof(short);
  float* bcomb  = (float*)w;                w += 512 * sizeof(float);
  int* counts   = (int*)w;                  w += NV * sizeof(int);
  int* counts2  = (int*)w;                  w += NV * sizeof(int);
  int* slots    = (int*)w;                  w += (size_t)NV * SLOT_CAP * sizeof(int);
  _Float16* xh1 = (_Float16*)w;

  const size_t base_end = 512 * 256 * sizeof(short) + 512 * sizeof(float)
                        + 2 * (size_t)NV * sizeof(int)
                        + (size_t)NV * SLOT_CAP * sizeof(int);  // ~26.7 MB

  // bf16 msg lives in the low 256B of each 512B out_c row (lstm block b reads
  // only the rows it later overwrites). xh0 = out_h region: 200K fp16 rows
  // * 256B == out_h size exactly; consumed by gather before lstm writes it.
  char* msgb = (char*)(out + (size_t)NV * D);
  _Float16* xh0 = (_Float16*)out;

  if (ws_size >= base_end) {
    size_t spare = (ws_size - base_end) / 256;  // extra fp16 rows in ws
    size_t cov = (size_t)XH0_CAP + spare;
    int ecut = (cov >= (size_t)NE) ? NE : (int)cov;
    wconv_kernel<<<512, 256, 0, stream>>>(W_ih, W_hh, b_ih, b_hh, Wcat, bcomb,
                                          counts, counts2);
    scatcon_kernel<<<SC_BLOCKS, 256, 0, stream>>>(eid, vid, counts, counts2,
                                                  slots, x_e, xh0, xh1, ecut);
    gather_mixed_kernel<<<NV / 4, 256, 0, stream>>>(x_e, xh0, xh1, counts,
                                                    counts2, slots, msgb);
  } else {
    wconv_kernel<<<512, 256, 0, stream>>>(W_ih, W_hh, b_ih, b_hh, Wcat, bcomb,
                                          counts, counts2);
    scatter_direct_kernel<<<(NNZN + 255) / 256, 256, 0, stream>>>(eid, vid,
                                                                  counts, slots);
    gather_kernel<<<NV / 4, 256, 0, stream>>>(x_e, counts, slots, msgb);
  }
  lstm_kernel<<<NV / 32, 256, 0, stream>>>(msgb, h_v, c_v, Wcat, bcomb, out);
}